// Round 6
// baseline (369.207 us; speedup 1.0000x reference)
//
#include <hip/hip_runtime.h>
#include <stdint.h>

#define BM 128
#define BN 128
#define KD 256     // K dimension; kernel assumes 256, B=8192

typedef __attribute__((ext_vector_type(4))) float f32x4;
typedef __attribute__((ext_vector_type(4))) int   i32x4;
typedef __attribute__((ext_vector_type(8))) int   i32x8;

// Kernel 1: per-row normalize, convert to fp8 e4m3 (OCP HW cvt); fp32 diag.
// Lane l handles elements [4l, 4l+4). Also zeroes d_out.
__global__ __launch_bounds__(256) void norm_kernel(
    const float* __restrict__ a, const float* __restrict__ b,
    unsigned int* __restrict__ an, unsigned int* __restrict__ bn,
    float* __restrict__ diag, float* __restrict__ out, int D) {
  if (blockIdx.x == 0 && threadIdx.x == 0) out[0] = 0.f;
  const int row = blockIdx.x * 4 + (threadIdx.x >> 6);
  const int l = threadIdx.x & 63;
  const float4 av = ((const float4*)(a + (size_t)row * D))[l];
  const float4 bv = ((const float4*)(b + (size_t)row * D))[l];
  float ssa = av.x*av.x + av.y*av.y + av.z*av.z + av.w*av.w;
  float ssb = bv.x*bv.x + bv.y*bv.y + bv.z*bv.z + bv.w*bv.w;
  float dot = av.x*bv.x + av.y*bv.y + av.z*bv.z + av.w*bv.w;
  for (int off = 1; off < 64; off <<= 1) {
    ssa += __shfl_xor(ssa, off, 64);
    ssb += __shfl_xor(ssb, off, 64);
    dot += __shfl_xor(dot, off, 64);
  }
  const float inva = 1.0f / sqrtf(ssa);
  const float invb = 1.0f / sqrtf(ssb);
  if (l == 0) diag[row] = dot * inva * invb;
  int pa = 0, pb = 0;
  pa = __builtin_amdgcn_cvt_pk_fp8_f32(av.x * inva, av.y * inva, pa, 0);
  pa = __builtin_amdgcn_cvt_pk_fp8_f32(av.z * inva, av.w * inva, pa, 1);
  pb = __builtin_amdgcn_cvt_pk_fp8_f32(bv.x * invb, bv.y * invb, pb, 0);
  pb = __builtin_amdgcn_cvt_pk_fp8_f32(bv.z * invb, bv.w * invb, pb, 1);
  an[(size_t)row * (D / 4) + l] = (unsigned int)pa;
  bn[(size_t)row * (D / 4) + l] = (unsigned int)pb;
}

// Kernel 2: r0-staging x r5-epilogue hybrid.
// Grid = 4096 single-tile blocks, 256 threads (4 waves, 2x2 grid: wave
// (wm,wn) owns the 64x64 quadrant). Both A and B staged COALESCED via
// global_load_lds in 2 phases of BK=128 through 33KB LDS -> 4 blocks/CU
// (r0's turnover, the only latency-hiding that has worked on this op).
// This removes r5's bottleneck: the per-wave scattered B-frag loads
// (16 L2 lines per instr, ~540MB of line requests ~= 69us request-bound).
// Dual-GEMM epilogue (r5): wave computes C (af x bf) AND C' (bf x af,
// operands already in regs). MFMA C/D layout is col=lane-local, so
// col-max of C = column partials, col-max of C' = ROW partials; both
// fold in-register + 2 shfl_xor. No bpermute chains, no red-overlay,
// no lds_col, no epilogue barrier. 3 barriers/block total.
// XOR swizzle (within 8x16B chunks of each 128B row): stored chunk of
// src chunk c, row r = c^(r&7), applied on the global source side;
// reads at p0/p1 undo it -> ds_read_b128 max 2-way (free).
__global__ __launch_bounds__(256, 4) void gemm_max_kernel(
    const unsigned char* __restrict__ an, const unsigned char* __restrict__ bn,
    const int* __restrict__ labels,
    float* __restrict__ row_part, float* __restrict__ col_part, int B) {
  __shared__ __align__(16) unsigned char sA[BM * 128];  // 16 KB (one phase)
  __shared__ __align__(16) unsigned char sB[BN * 128];  // 16 KB

  const int tid  = threadIdx.x;
  const int lane = tid & 63;
  const int w    = tid >> 6;            // 0..3
  const int wm   = w >> 1, wn = w & 1;  // 2x2 wave grid (64x64 quadrants)
  const int tj   = blockIdx.x & 63;     // fast-varying: A-panel L2 reuse
  const int ti   = blockIdx.x >> 6;

  // fragment decomposition
  const int fr = lane & 15;             // m/n index
  const int hi = lane >> 4;             // k-quad: k = hi*32..+31 within phase
  const int p0 = ((2 * hi)     ^ (fr & 7)) * 16;
  const int p1 = ((2 * hi + 1) ^ (fr & 7)) * 16;

  // ---- coalesced swizzled stage of one BK=128 phase (A+B, 8 gl_lds/thread) ----
  const int srr = lane >> 3;            // row within 8-row group
  const int scc = lane & 7;             // dst chunk position 0..7
  auto stage = [&](int it) {
    #pragma unroll
    for (int i = 0; i < 4; ++i) {
      const int r0  = w * 32 + i * 8;   // wave-uniform 8-row base
      const int row = r0 + srr;
      const int g   = scc ^ (row & 7);  // source chunk stored at position scc
      const unsigned char* ga = an + (size_t)(ti * BM + row) * KD + it * 128 + g * 16;
      const unsigned char* gb = bn + (size_t)(tj * BN + row) * KD + it * 128 + g * 16;
      __builtin_amdgcn_global_load_lds(
          (const __attribute__((address_space(1))) void*)ga,
          (__attribute__((address_space(3))) void*)(sA + r0 * 128 + lane * 16), 16, 0, 0);
      __builtin_amdgcn_global_load_lds(
          (const __attribute__((address_space(1))) void*)gb,
          (__attribute__((address_space(3))) void*)(sB + r0 * 128 + lane * 16), 16, 0, 0);
    }
  };

  const int SC = 0x7F7F7F7F;            // E8M0 = 1.0 in all byte slots
  f32x4 acc[4][4], at[4][4];            // C and C' (transposed) quadrants
  #pragma unroll
  for (int mt = 0; mt < 4; ++mt)
    #pragma unroll
    for (int nt = 0; nt < 4; ++nt) {
      acc[mt][nt] = (f32x4){0.f, 0.f, 0.f, 0.f};
      at[mt][nt]  = (f32x4){0.f, 0.f, 0.f, 0.f};
    }

  #pragma unroll
  for (int it = 0; it < 2; ++it) {
    stage(it);
    __syncthreads();                    // phase staged

    i32x8 bf[4];
    #pragma unroll
    for (int nt = 0; nt < 4; ++nt) {
      const unsigned char* rb = sB + (wn * 64 + nt * 16 + fr) * 128;
      bf[nt] = __builtin_shufflevector(*(const i32x4*)(rb + p0),
                                       *(const i32x4*)(rb + p1),
                                       0, 1, 2, 3, 4, 5, 6, 7);
    }
    #pragma unroll
    for (int mt = 0; mt < 4; ++mt) {
      const unsigned char* ra = sA + (wm * 64 + mt * 16 + fr) * 128;
      const i32x8 af = __builtin_shufflevector(*(const i32x4*)(ra + p0),
                                               *(const i32x4*)(ra + p1),
                                               0, 1, 2, 3, 4, 5, 6, 7);
      #pragma unroll
      for (int nt = 0; nt < 4; ++nt) {
        acc[mt][nt] = __builtin_amdgcn_mfma_scale_f32_16x16x128_f8f6f4(
            af, bf[nt], acc[mt][nt], 0, 0, 0, SC, 0, SC);
        at[mt][nt] = __builtin_amdgcn_mfma_scale_f32_16x16x128_f8f6f4(
            bf[nt], af, at[mt][nt], 0, 0, 0, SC, 0, SC);
      }
    }
    if (it == 0) __syncthreads();       // all reads done before restage
  }

  // ---- Epilogue: all lane-local + 2 shfl folds; no barriers ----
  // C  layout: acc[mt][nt][r] = sm[i,j], i = ti*BM+wm*64+mt*16+hi*4+r,
  //                                      j = tj*BN+wn*64+nt*16+fr
  // C' layout: at[mt][nt][r]  = sm[i,j], i = ti*BM+wm*64+mt*16+fr,
  //                                      j = tj*BN+wn*64+nt*16+hi*4+r
  int labc[4], la[4];
  i32x4 lv[4], labj[4];
  #pragma unroll
  for (int t = 0; t < 4; ++t) {
    labc[t] = labels[tj * BN + wn * 64 + t * 16 + fr];
    la[t]   = labels[ti * BM + wm * 64 + t * 16 + fr];
    lv[t]   = *(const i32x4*)&labels[ti * BM + wm * 64 + t * 16 + hi * 4];
    labj[t] = *(const i32x4*)&labels[tj * BN + wn * 64 + t * 16 + hi * 4];
  }

  // Column partials from C (masked max over i; i spans mt,r here, hi by fold)
  float cp[4] = {-1e9f, -1e9f, -1e9f, -1e9f};
  #pragma unroll
  for (int mt = 0; mt < 4; ++mt)
    #pragma unroll
    for (int r = 0; r < 4; ++r) {
      const int l0 = lv[mt][r];
      #pragma unroll
      for (int nt = 0; nt < 4; ++nt)
        cp[nt] = fmaxf(cp[nt], (l0 != labc[nt]) ? acc[mt][nt][r] : -1e9f);
    }
  #pragma unroll
  for (int nt = 0; nt < 4; ++nt) {
    float c = cp[nt];
    c = fmaxf(c, __shfl_xor(c, 16, 64));
    c = fmaxf(c, __shfl_xor(c, 32, 64));
    if (hi == 0)
      col_part[(size_t)(ti * 2 + wm) * B + tj * BN + wn * 64 + nt * 16 + fr] = c;
  }

  // Row partials from C' (masked max over j; j spans nt,r here, hi by fold)
  #pragma unroll
  for (int mt = 0; mt < 4; ++mt) {
    const int lam = la[mt];
    float rm = -1e9f;
    #pragma unroll
    for (int nt = 0; nt < 4; ++nt)
      #pragma unroll
      for (int r = 0; r < 4; ++r)
        rm = fmaxf(rm, (lam != labj[nt][r]) ? at[mt][nt][r] : -1e9f);
    rm = fmaxf(rm, __shfl_xor(rm, 16, 64));
    rm = fmaxf(rm, __shfl_xor(rm, 32, 64));
    if (hi == 0)
      row_part[(size_t)(tj * 2 + wn) * B + ti * BM + wm * 64 + mt * 16 + fr] = rm;
  }
}

// Kernel 3: reduce per-slot maxes -> M; threshold; per-row loss; atomicAdd.
// Row dir: Tr=128 slots (tj x wn); col dir: Tc=128 (ti x wm). Wave-per-
// quarter split for load parallelism (grid = 2B/64 = 256 blocks).
__global__ __launch_bounds__(256) void finalize_kernel(
    const float* __restrict__ row_part, const float* __restrict__ col_part,
    const float* __restrict__ diag, int B, int Tr, int Tc,
    float* __restrict__ out) {
  const int ln = threadIdx.x & 63;
  const int q  = threadIdx.x >> 6;           // wave = quarter of the T range
  const int item = blockIdx.x * 64 + ln;     // 0..2B-1
  const bool isrow = item < B;
  const int i = isrow ? item : item - B;
  const float* part = isrow ? row_part : col_part;
  const int T = isrow ? Tr : Tc;
  const int tpq = (T + 3) >> 2;
  const int t1 = min(T, (q + 1) * tpq);
  float m = -1e9f;
  for (int t = q * tpq; t < t1; ++t) m = fmaxf(m, part[(size_t)t * B + i]);
  __shared__ float smq[4][64];
  smq[q][ln] = m;
  __syncthreads();
  if (q == 0) {
    m = fmaxf(fmaxf(smq[0][ln], smq[1][ln]), fmaxf(smq[2][ln], smq[3][ln]));
    const float d = diag[i];
    float loss = 0.f;
    if ((d < 1.0f - 1e-5f) && (m + 0.2f > d)) {
      loss = fmaxf(0.2f * d * d - 0.7f * d + 0.5f, 0.f) +
             fmaxf(0.9f * m * m - 0.4f * m + 0.03f, 0.f);
    }
    for (int off = 1; off < 64; off <<= 1) loss += __shfl_xor(loss, off, 64);
    if (ln == 0) atomicAdd(out, loss / (float)B);
  }
}

extern "C" void kernel_launch(void* const* d_in, const int* in_sizes, int n_in,
                              void* d_out, int out_size, void* d_ws, size_t ws_size,
                              hipStream_t stream) {
  const float* a      = (const float*)d_in[0];
  const float* b      = (const float*)d_in[1];
  const int*   labels = (const int*)d_in[2];
  const int B = in_sizes[2];
  const int D = in_sizes[0] / B;       // 256
  const int Tr = (B / BN) * 2;         // 128 row partial slots (tj x wn)
  const int Tc = (B / BM) * 2;         // 128 col partial slots (ti x wm)

  char* ws = (char*)d_ws;
  unsigned char* an = (unsigned char*)ws;                    // B*D fp8
  unsigned char* bn = (unsigned char*)(ws + (size_t)B * D);  // B*D fp8
  float* diag     = (float*)(ws + (size_t)2 * B * D);        // B*4
  float* row_part = diag + B;                                // Tr*B*4
  float* col_part = row_part + (size_t)Tr * B;               // Tc*B*4

  norm_kernel<<<B / 4, 256, 0, stream>>>(a, b, (unsigned int*)an,
                                         (unsigned int*)bn, diag,
                                         (float*)d_out, D);

  gemm_max_kernel<<<(B / BM) * (B / BN), 256, 0, stream>>>(
      an, bn, labels, row_part, col_part, B);

  finalize_kernel<<<(2 * B) / 64, 256, 0, stream>>>(
      row_part, col_part, diag, B, Tr, Tc, (float*)d_out);
}

// Round 7
// 330.927 us; speedup vs baseline: 1.1157x; 1.1157x over previous
//
#include <hip/hip_runtime.h>
#include <stdint.h>

#define BM 128
#define BN 128
#define KD 256     // K dimension; kernel assumes 256, B=8192

typedef __attribute__((ext_vector_type(4))) float f32x4;
typedef __attribute__((ext_vector_type(4))) int   i32x4;
typedef __attribute__((ext_vector_type(8))) int   i32x8;

// Kernel 1: per-row normalize, convert to fp8 e4m3 (OCP HW cvt); fp32 diag.
// Lane l handles elements [4l, 4l+4). Also zeroes d_out.
__global__ __launch_bounds__(256) void norm_kernel(
    const float* __restrict__ a, const float* __restrict__ b,
    unsigned int* __restrict__ an, unsigned int* __restrict__ bn,
    float* __restrict__ diag, float* __restrict__ out, int D) {
  if (blockIdx.x == 0 && threadIdx.x == 0) out[0] = 0.f;
  const int row = blockIdx.x * 4 + (threadIdx.x >> 6);
  const int l = threadIdx.x & 63;
  const float4 av = ((const float4*)(a + (size_t)row * D))[l];
  const float4 bv = ((const float4*)(b + (size_t)row * D))[l];
  float ssa = av.x*av.x + av.y*av.y + av.z*av.z + av.w*av.w;
  float ssb = bv.x*bv.x + bv.y*bv.y + bv.z*bv.z + bv.w*bv.w;
  float dot = av.x*bv.x + av.y*bv.y + av.z*bv.z + av.w*bv.w;
  for (int off = 1; off < 64; off <<= 1) {
    ssa += __shfl_xor(ssa, off, 64);
    ssb += __shfl_xor(ssb, off, 64);
    dot += __shfl_xor(dot, off, 64);
  }
  const float inva = 1.0f / sqrtf(ssa);
  const float invb = 1.0f / sqrtf(ssb);
  if (l == 0) diag[row] = dot * inva * invb;
  int pa = 0, pb = 0;
  pa = __builtin_amdgcn_cvt_pk_fp8_f32(av.x * inva, av.y * inva, pa, 0);
  pa = __builtin_amdgcn_cvt_pk_fp8_f32(av.z * inva, av.w * inva, pa, 1);
  pb = __builtin_amdgcn_cvt_pk_fp8_f32(bv.x * invb, bv.y * invb, pb, 0);
  pb = __builtin_amdgcn_cvt_pk_fp8_f32(bv.z * invb, bv.w * invb, pb, 1);
  an[(size_t)row * (D / 4) + l] = (unsigned int)pa;
  bn[(size_t)row * (D / 4) + l] = (unsigned int)pb;
}

// Kernel 2: r0-staging x r5-epilogue hybrid, REGISTER-SAFE geometry
// (round-6 post-mortem: 64x64-quadrant dual-GEMM needs 170 VGPR > the 128
// cap -> accumulators spilled to scratch -> 1.3 GB HBM traffic, 296us.
// Fix: r5's proven 64x32-per-wave shape: acc 32 + at 32 + bf 16 + af 8
// ~= 110 live VGPR < 128).
// Grid = 4096 single-tile blocks, 512 threads (8 waves, 2x4: wave (wm,wn)
// owns 64 rows x 32 cols). Both A and B staged COALESCED via
// global_load_lds in 2 phases of BK=128 through 33KB LDS (single buffer,
// 3 barriers/block); 2 blocks/CU (16 waves) so the other block's compute
// covers this block's stage drain (m114 overlap -- the only mechanism
// that has worked on this op).
// Dual-GEMM epilogue (r5, proven): wave computes C (af x bf) AND
// C' (bf x af; operands already in registers, zero extra memory traffic).
// MFMA C/D layout is col=lane-local, so col-max of C = column partials,
// col-max of C' = ROW partials; both fold in-register + 2 shfl_xor.
// No bpermutes, no LDS reduction, no epilogue barrier.
// XOR swizzle (r0's proven scheme, within the 8 16B-chunks of each 128B
// phase-row): source chunk g stored at position g^(row&7), applied on the
// GLOBAL source address (gl_lds LDS dest must be lane-contiguous); reads
// at p0/p1 undo it -> ds_read_b128 is 2-way max (free).
__global__ __launch_bounds__(512, 4) void gemm_max_kernel(
    const unsigned char* __restrict__ an, const unsigned char* __restrict__ bn,
    const int* __restrict__ labels,
    float* __restrict__ row_part, float* __restrict__ col_part, int B) {
  __shared__ __align__(16) unsigned char sA[BM * 128];  // 16 KB (one phase)
  __shared__ __align__(16) unsigned char sB[BN * 128];  // 16 KB

  const int tid  = threadIdx.x;
  const int lane = tid & 63;
  const int w    = tid >> 6;            // 0..7
  const int wm   = w >> 2, wn = w & 3;  // 2x4 wave grid: 64 rows x 32 cols
  const int tj   = blockIdx.x & 63;     // fast-varying: A-panel L2 reuse
  const int ti   = blockIdx.x >> 6;

  // staging decomposition: each gl_lds instr stages 8 rows x 8 chunks = 1KB
  const int srr = lane >> 3;            // row within 8-row group
  const int scc = lane & 7;             // dst chunk position 0..7
  // fragment decomposition
  const int fr = lane & 15;             // m/n index
  const int hi = lane >> 4;             // k-quad: k = hi*32..+31 within phase
  const int p0 = ((2 * hi)     ^ (fr & 7)) * 16;
  const int p1 = ((2 * hi + 1) ^ (fr & 7)) * 16;

  // ---- coalesced swizzled stage of one BK=128 phase (A+B, 4 gl_lds/thread) ----
  auto stage = [&](int it) {
    #pragma unroll
    for (int i = 0; i < 2; ++i) {
      const int r0  = i * 64 + w * 8;   // wave-uniform 8-row base
      const int row = r0 + srr;
      const int g   = scc ^ (row & 7);  // source chunk stored at position scc
      const unsigned char* ga = an + (size_t)(ti * BM + row) * KD + it * 128 + g * 16;
      const unsigned char* gb = bn + (size_t)(tj * BN + row) * KD + it * 128 + g * 16;
      __builtin_amdgcn_global_load_lds(
          (const __attribute__((address_space(1))) void*)ga,
          (__attribute__((address_space(3))) void*)(sA + r0 * 128 + lane * 16), 16, 0, 0);
      __builtin_amdgcn_global_load_lds(
          (const __attribute__((address_space(1))) void*)gb,
          (__attribute__((address_space(3))) void*)(sB + r0 * 128 + lane * 16), 16, 0, 0);
    }
  };

  const int SC = 0x7F7F7F7F;            // E8M0 = 1.0 in all byte slots
  f32x4 acc[4][2], at[4][2];            // C and C' (32 + 32 VGPR)
  #pragma unroll
  for (int mt = 0; mt < 4; ++mt)
    #pragma unroll
    for (int nt = 0; nt < 2; ++nt) {
      acc[mt][nt] = (f32x4){0.f, 0.f, 0.f, 0.f};
      at[mt][nt]  = (f32x4){0.f, 0.f, 0.f, 0.f};
    }

  #pragma unroll
  for (int it = 0; it < 2; ++it) {
    stage(it);
    __syncthreads();                    // phase staged

    i32x8 bf[2];
    #pragma unroll
    for (int nt = 0; nt < 2; ++nt) {
      const unsigned char* rb = sB + (wn * 32 + nt * 16 + fr) * 128;
      bf[nt] = __builtin_shufflevector(*(const i32x4*)(rb + p0),
                                       *(const i32x4*)(rb + p1),
                                       0, 1, 2, 3, 4, 5, 6, 7);
    }
    #pragma unroll
    for (int mt = 0; mt < 4; ++mt) {
      const unsigned char* ra = sA + (wm * 64 + mt * 16 + fr) * 128;
      const i32x8 af = __builtin_shufflevector(*(const i32x4*)(ra + p0),
                                               *(const i32x4*)(ra + p1),
                                               0, 1, 2, 3, 4, 5, 6, 7);
      acc[mt][0] = __builtin_amdgcn_mfma_scale_f32_16x16x128_f8f6f4(
          af, bf[0], acc[mt][0], 0, 0, 0, SC, 0, SC);
      acc[mt][1] = __builtin_amdgcn_mfma_scale_f32_16x16x128_f8f6f4(
          af, bf[1], acc[mt][1], 0, 0, 0, SC, 0, SC);
      at[mt][0] = __builtin_amdgcn_mfma_scale_f32_16x16x128_f8f6f4(
          bf[0], af, at[mt][0], 0, 0, 0, SC, 0, SC);
      at[mt][1] = __builtin_amdgcn_mfma_scale_f32_16x16x128_f8f6f4(
          bf[1], af, at[mt][1], 0, 0, 0, SC, 0, SC);
    }
    if (it == 0) __syncthreads();       // all reads done before restage
  }

  // ---- Epilogue: all lane-local + 2 shfl folds; no barriers ----
  // C  layout: acc[mt][nt][r] = sm[i,j], i = ti*BM+wm*64+mt*16+hi*4+r,
  //                                      j = tj*BN+wn*32+nt*16+fr
  // C' layout: at[mt][nt][r]  = sm[i,j], i = ti*BM+wm*64+mt*16+fr,
  //                                      j = tj*BN+wn*32+nt*16+hi*4+r
  int labc[2], la[4];
  i32x4 lv[4], labj[2];
  #pragma unroll
  for (int t = 0; t < 4; ++t) {
    la[t] = labels[ti * BM + wm * 64 + t * 16 + fr];
    lv[t] = *(const i32x4*)&labels[ti * BM + wm * 64 + t * 16 + hi * 4];
  }
  #pragma unroll
  for (int t = 0; t < 2; ++t) {
    labc[t] = labels[tj * BN + wn * 32 + t * 16 + fr];
    labj[t] = *(const i32x4*)&labels[tj * BN + wn * 32 + t * 16 + hi * 4];
  }

  // Column partials from C (masked max over i; mt,r lane-local, hi by fold)
  float cp[2] = {-1e9f, -1e9f};
  #pragma unroll
  for (int mt = 0; mt < 4; ++mt)
    #pragma unroll
    for (int r = 0; r < 4; ++r) {
      const int l0 = lv[mt][r];
      cp[0] = fmaxf(cp[0], (l0 != labc[0]) ? acc[mt][0][r] : -1e9f);
      cp[1] = fmaxf(cp[1], (l0 != labc[1]) ? acc[mt][1][r] : -1e9f);
    }
  #pragma unroll
  for (int nt = 0; nt < 2; ++nt) {
    float c = cp[nt];
    c = fmaxf(c, __shfl_xor(c, 16, 64));
    c = fmaxf(c, __shfl_xor(c, 32, 64));
    if (hi == 0)
      col_part[(size_t)(ti * 2 + wm) * B + tj * BN + wn * 32 + nt * 16 + fr] = c;
  }

  // Row partials from C' (masked max over j; nt,r lane-local, hi by fold)
  #pragma unroll
  for (int mt = 0; mt < 4; ++mt) {
    const int lam = la[mt];
    float rm = -1e9f;
    #pragma unroll
    for (int nt = 0; nt < 2; ++nt)
      #pragma unroll
      for (int r = 0; r < 4; ++r)
        rm = fmaxf(rm, (lam != labj[nt][r]) ? at[mt][nt][r] : -1e9f);
    rm = fmaxf(rm, __shfl_xor(rm, 16, 64));
    rm = fmaxf(rm, __shfl_xor(rm, 32, 64));
    if (hi == 0)
      row_part[(size_t)(tj * 4 + wn) * B + ti * BM + wm * 64 + mt * 16 + fr] = rm;
  }
}

// Kernel 3: reduce per-slot maxes -> M; threshold; per-row loss; atomicAdd.
// Row dir: Tr=256 slots (tj x wn); col dir: Tc=128 (ti x wm). Wave-per-
// quarter split for load parallelism (grid = 2B/64 = 256 blocks).
__global__ __launch_bounds__(256) void finalize_kernel(
    const float* __restrict__ row_part, const float* __restrict__ col_part,
    const float* __restrict__ diag, int B, int Tr, int Tc,
    float* __restrict__ out) {
  const int ln = threadIdx.x & 63;
  const int q  = threadIdx.x >> 6;           // wave = quarter of the T range
  const int item = blockIdx.x * 64 + ln;     // 0..2B-1
  const bool isrow = item < B;
  const int i = isrow ? item : item - B;
  const float* part = isrow ? row_part : col_part;
  const int T = isrow ? Tr : Tc;
  const int tpq = (T + 3) >> 2;
  const int t1 = min(T, (q + 1) * tpq);
  float m = -1e9f;
  for (int t = q * tpq; t < t1; ++t) m = fmaxf(m, part[(size_t)t * B + i]);
  __shared__ float smq[4][64];
  smq[q][ln] = m;
  __syncthreads();
  if (q == 0) {
    m = fmaxf(fmaxf(smq[0][ln], smq[1][ln]), fmaxf(smq[2][ln], smq[3][ln]));
    const float d = diag[i];
    float loss = 0.f;
    if ((d < 1.0f - 1e-5f) && (m + 0.2f > d)) {
      loss = fmaxf(0.2f * d * d - 0.7f * d + 0.5f, 0.f) +
             fmaxf(0.9f * m * m - 0.4f * m + 0.03f, 0.f);
    }
    for (int off = 1; off < 64; off <<= 1) loss += __shfl_xor(loss, off, 64);
    if (ln == 0) atomicAdd(out, loss / (float)B);
  }
}

extern "C" void kernel_launch(void* const* d_in, const int* in_sizes, int n_in,
                              void* d_out, int out_size, void* d_ws, size_t ws_size,
                              hipStream_t stream) {
  const float* a      = (const float*)d_in[0];
  const float* b      = (const float*)d_in[1];
  const int*   labels = (const int*)d_in[2];
  const int B = in_sizes[2];
  const int D = in_sizes[0] / B;       // 256
  const int Tr = (B / BN) * 4;         // 256 row partial slots (tj x wn)
  const int Tc = (B / BM) * 2;         // 128 col partial slots (ti x wm)

  char* ws = (char*)d_ws;
  unsigned char* an = (unsigned char*)ws;                    // B*D fp8
  unsigned char* bn = (unsigned char*)(ws + (size_t)B * D);  // B*D fp8
  float* diag     = (float*)(ws + (size_t)2 * B * D);        // B*4
  float* row_part = diag + B;                                // Tr*B*4
  float* col_part = row_part + (size_t)Tr * B;               // Tc*B*4

  norm_kernel<<<B / 4, 256, 0, stream>>>(a, b, (unsigned int*)an,
                                         (unsigned int*)bn, diag,
                                         (float*)d_out, D);

  gemm_max_kernel<<<(B / BM) * (B / BN), 512, 0, stream>>>(
      an, bn, labels, row_part, col_part, B);

  finalize_kernel<<<(2 * B) / 64, 256, 0, stream>>>(
      row_part, col_part, diag, B, Tr, Tc, (float*)d_out);
}

// Round 8
// 134.442 us; speedup vs baseline: 2.7462x; 2.4615x over previous
//
#include <hip/hip_runtime.h>
#include <stdint.h>

#define BM 128
#define BN 64
#define KD 256     // K dimension; kernel assumes 256, B=8192

typedef __attribute__((ext_vector_type(4))) float f32x4;
typedef __attribute__((ext_vector_type(4))) int   i32x4;
typedef __attribute__((ext_vector_type(8))) int   i32x8;

// Kernel 1: per-row normalize, convert to fp8 e4m3 (OCP HW cvt); fp32 diag.
// Lane l handles elements [4l, 4l+4). Also zeroes d_out.
__global__ __launch_bounds__(256) void norm_kernel(
    const float* __restrict__ a, const float* __restrict__ b,
    unsigned int* __restrict__ an, unsigned int* __restrict__ bn,
    float* __restrict__ diag, float* __restrict__ out, int D) {
  if (blockIdx.x == 0 && threadIdx.x == 0) out[0] = 0.f;
  const int row = blockIdx.x * 4 + (threadIdx.x >> 6);
  const int l = threadIdx.x & 63;
  const float4 av = ((const float4*)(a + (size_t)row * D))[l];
  const float4 bv = ((const float4*)(b + (size_t)row * D))[l];
  float ssa = av.x*av.x + av.y*av.y + av.z*av.z + av.w*av.w;
  float ssb = bv.x*bv.x + bv.y*bv.y + bv.z*bv.z + bv.w*bv.w;
  float dot = av.x*bv.x + av.y*bv.y + av.z*bv.z + av.w*bv.w;
  for (int off = 1; off < 64; off <<= 1) {
    ssa += __shfl_xor(ssa, off, 64);
    ssb += __shfl_xor(ssb, off, 64);
    dot += __shfl_xor(dot, off, 64);
  }
  const float inva = 1.0f / sqrtf(ssa);
  const float invb = 1.0f / sqrtf(ssb);
  if (l == 0) diag[row] = dot * inva * invb;
  int pa = 0, pb = 0;
  pa = __builtin_amdgcn_cvt_pk_fp8_f32(av.x * inva, av.y * inva, pa, 0);
  pa = __builtin_amdgcn_cvt_pk_fp8_f32(av.z * inva, av.w * inva, pa, 1);
  pb = __builtin_amdgcn_cvt_pk_fp8_f32(bv.x * invb, bv.y * invb, pb, 0);
  pb = __builtin_amdgcn_cvt_pk_fp8_f32(bv.z * invb, bv.w * invb, pb, 1);
  an[(size_t)row * (D / 4) + l] = (unsigned int)pa;
  bn[(size_t)row * (D / 4) + l] = (unsigned int)pb;
}

// Kernel 2: dual-GEMM fp8 tile + lane-local maxes, REGISTER-SAFE v2.
// Round-7 post-mortem: the dual-GEMM working set peaks ~140 VGPR; any
// launch_bounds cap <=128 spills it (r6: 1.3GB scratch, r7: 1.2GB).
// Fix: 256-thread blocks (4 waves), __launch_bounds__(256,3) -> cap
// 512/3 = 170 >= 140 -> no spill, and deterministically 3 waves/SIMD =
// 3 BLOCKS/CU co-resident -- the r0 turnover mechanism that is the only
// latency-hiding proven to work on this op.
// Tile 128x64, wave (wm,wn) of the 2x2 grid owns 64 rows x 32 cols (the
// r5-proven fitting shape). SINGLE K=256 phase: sA 32KB + sB 16KB = 48KB
// (x3 blocks = 144 <= 160). Staging completes before the MFMA loop, so
// staging address registers are dead during compute (the r7 live-range
// trap). ONE barrier per block, zero epilogue barriers.
// Dual-GEMM epilogue (r5/r7-proven correct): wave computes C (af x bf)
// AND C' (bf x af; operands already in registers). MFMA C/D layout is
// col=lane-local, so col-max of C = column partials and col-max of C' =
// ROW partials; both fold in-register + 2 shfl_xor, direct stores.
// XOR swizzle (r2-proven full-row scheme): source chunk g of row r stored
// at position ((g&7)^(r&7))|(g&8), applied on the GLOBAL source address;
// reads at it*128 + p0/p1 undo it (XOR never crosses the 128B half).
__global__ __launch_bounds__(256, 3) void gemm_max_kernel(
    const unsigned char* __restrict__ an, const unsigned char* __restrict__ bn,
    const int* __restrict__ labels,
    float* __restrict__ row_part, float* __restrict__ col_part, int B) {
  __shared__ __align__(16) unsigned char sA[BM * KD];   // 32 KB
  __shared__ __align__(16) unsigned char sB[BN * KD];   // 16 KB

  const int tid  = threadIdx.x;
  const int lane = tid & 63;
  const int w    = tid >> 6;            // 0..3
  const int wm   = w >> 1, wn = w & 1;  // 2x2 wave grid: 64 rows x 32 cols
  const int tj   = blockIdx.x & 127;    // fast-varying: A-tile L2 reuse
  const int ti   = blockIdx.x >> 7;

  // staging decomposition: each gl_lds instr stages 4 rows x 16 chunks = 1KB
  const int sr = lane >> 4;             // row within 4-row group
  const int sc = lane & 15;             // dst 16B-chunk position 0..15
  // fragment decomposition
  const int fr = lane & 15;             // m/n index
  const int hi = lane >> 4;             // k-quad: k = it*128 + hi*32..+31
  const int p0 = ((2 * hi)     ^ (fr & 7)) * 16;
  const int p1 = ((2 * hi + 1) ^ (fr & 7)) * 16;

  // ---- Stage full K=256 panels: A 8 instrs/thread, B 4 instrs/thread ----
  {
    const int g = ((sc & 7) ^ ((sr + w * 4) & 7)) | (sc & 8);  // row&7 == (sr+w*4)&7 for r0%16==0
    #pragma unroll
    for (int i = 0; i < 8; ++i) {
      const int r0  = i * 16 + w * 4;   // wave-uniform 4-row base (mult of 16 per wave pattern)
      const int row = r0 + sr;
      const unsigned char* ga = an + (size_t)(ti * BM + row) * KD + g * 16;
      __builtin_amdgcn_global_load_lds(
          (const __attribute__((address_space(1))) void*)ga,
          (__attribute__((address_space(3))) void*)(sA + r0 * KD + lane * 16), 16, 0, 0);
    }
    #pragma unroll
    for (int i = 0; i < 4; ++i) {
      const int r0  = i * 16 + w * 4;
      const int row = r0 + sr;
      const unsigned char* gb = bn + (size_t)(tj * BN + row) * KD + g * 16;
      __builtin_amdgcn_global_load_lds(
          (const __attribute__((address_space(1))) void*)gb,
          (__attribute__((address_space(3))) void*)(sB + r0 * KD + lane * 16), 16, 0, 0);
    }
  }
  __syncthreads();   // the only barrier

  const int SC = 0x7F7F7F7F;            // E8M0 = 1.0 in all byte slots
  f32x4 acc[4][2], at[4][2];            // C and C' (32 + 32 regs)
  #pragma unroll
  for (int mt = 0; mt < 4; ++mt)
    #pragma unroll
    for (int nt = 0; nt < 2; ++nt) {
      acc[mt][nt] = (f32x4){0.f, 0.f, 0.f, 0.f};
      at[mt][nt]  = (f32x4){0.f, 0.f, 0.f, 0.f};
    }

  #pragma unroll
  for (int it = 0; it < 2; ++it) {
    i32x8 bf[2];
    #pragma unroll
    for (int nt = 0; nt < 2; ++nt) {
      const unsigned char* rb = sB + (wn * 32 + nt * 16 + fr) * KD + it * 128;
      bf[nt] = __builtin_shufflevector(*(const i32x4*)(rb + p0),
                                       *(const i32x4*)(rb + p1),
                                       0, 1, 2, 3, 4, 5, 6, 7);
    }
    #pragma unroll
    for (int mt = 0; mt < 4; ++mt) {
      const unsigned char* ra = sA + (wm * 64 + mt * 16 + fr) * KD + it * 128;
      const i32x8 af = __builtin_shufflevector(*(const i32x4*)(ra + p0),
                                               *(const i32x4*)(ra + p1),
                                               0, 1, 2, 3, 4, 5, 6, 7);
      acc[mt][0] = __builtin_amdgcn_mfma_scale_f32_16x16x128_f8f6f4(
          af, bf[0], acc[mt][0], 0, 0, 0, SC, 0, SC);
      acc[mt][1] = __builtin_amdgcn_mfma_scale_f32_16x16x128_f8f6f4(
          af, bf[1], acc[mt][1], 0, 0, 0, SC, 0, SC);
      at[mt][0] = __builtin_amdgcn_mfma_scale_f32_16x16x128_f8f6f4(
          bf[0], af, at[mt][0], 0, 0, 0, SC, 0, SC);
      at[mt][1] = __builtin_amdgcn_mfma_scale_f32_16x16x128_f8f6f4(
          bf[1], af, at[mt][1], 0, 0, 0, SC, 0, SC);
    }
  }

  // ---- Epilogue: all lane-local + 2 shfl folds; no barriers ----
  // C  layout: acc[mt][nt][r] = sm[i,j], i = ti*BM+wm*64+mt*16+hi*4+r,
  //                                      j = tj*BN+wn*32+nt*16+fr
  // C' layout: at[mt][nt][r]  = sm[i,j], i = ti*BM+wm*64+mt*16+fr,
  //                                      j = tj*BN+wn*32+nt*16+hi*4+r
  int labc[2], la[4];
  i32x4 lv[4], labj[2];
  #pragma unroll
  for (int t = 0; t < 4; ++t) {
    la[t] = labels[ti * BM + wm * 64 + t * 16 + fr];
    lv[t] = *(const i32x4*)&labels[ti * BM + wm * 64 + t * 16 + hi * 4];
  }
  #pragma unroll
  for (int t = 0; t < 2; ++t) {
    labc[t] = labels[tj * BN + wn * 32 + t * 16 + fr];
    labj[t] = *(const i32x4*)&labels[tj * BN + wn * 32 + t * 16 + hi * 4];
  }

  // Column partials from C (masked max over i; mt,r lane-local, hi by fold)
  float cp[2] = {-1e9f, -1e9f};
  #pragma unroll
  for (int mt = 0; mt < 4; ++mt)
    #pragma unroll
    for (int r = 0; r < 4; ++r) {
      const int l0 = lv[mt][r];
      cp[0] = fmaxf(cp[0], (l0 != labc[0]) ? acc[mt][0][r] : -1e9f);
      cp[1] = fmaxf(cp[1], (l0 != labc[1]) ? acc[mt][1][r] : -1e9f);
    }
  #pragma unroll
  for (int nt = 0; nt < 2; ++nt) {
    float c = cp[nt];
    c = fmaxf(c, __shfl_xor(c, 16, 64));
    c = fmaxf(c, __shfl_xor(c, 32, 64));
    if (hi == 0)
      col_part[(size_t)(ti * 2 + wm) * B + tj * BN + wn * 32 + nt * 16 + fr] = c;
  }

  // Row partials from C' (masked max over j; nt,r lane-local, hi by fold)
  #pragma unroll
  for (int mt = 0; mt < 4; ++mt) {
    const int lam = la[mt];
    float rm = -1e9f;
    #pragma unroll
    for (int nt = 0; nt < 2; ++nt)
      #pragma unroll
      for (int r = 0; r < 4; ++r)
        rm = fmaxf(rm, (lam != labj[nt][r]) ? at[mt][nt][r] : -1e9f);
    rm = fmaxf(rm, __shfl_xor(rm, 16, 64));
    rm = fmaxf(rm, __shfl_xor(rm, 32, 64));
    if (hi == 0)
      row_part[(size_t)(tj * 2 + wn) * B + ti * BM + wm * 64 + mt * 16 + fr] = rm;
  }
}

// Kernel 3: reduce per-slot maxes -> M; threshold; per-row loss; atomicAdd.
// Row dir: Tr=256 slots (tj x wn); col dir: Tc=128 (ti x wm). Wave-per-
// quarter split for load parallelism (grid = 2B/64 = 256 blocks).
__global__ __launch_bounds__(256) void finalize_kernel(
    const float* __restrict__ row_part, const float* __restrict__ col_part,
    const float* __restrict__ diag, int B, int Tr, int Tc,
    float* __restrict__ out) {
  const int ln = threadIdx.x & 63;
  const int q  = threadIdx.x >> 6;           // wave = quarter of the T range
  const int item = blockIdx.x * 64 + ln;     // 0..2B-1
  const bool isrow = item < B;
  const int i = isrow ? item : item - B;
  const float* part = isrow ? row_part : col_part;
  const int T = isrow ? Tr : Tc;
  const int tpq = (T + 3) >> 2;
  const int t1 = min(T, (q + 1) * tpq);
  float m = -1e9f;
  for (int t = q * tpq; t < t1; ++t) m = fmaxf(m, part[(size_t)t * B + i]);
  __shared__ float smq[4][64];
  smq[q][ln] = m;
  __syncthreads();
  if (q == 0) {
    m = fmaxf(fmaxf(smq[0][ln], smq[1][ln]), fmaxf(smq[2][ln], smq[3][ln]));
    const float d = diag[i];
    float loss = 0.f;
    if ((d < 1.0f - 1e-5f) && (m + 0.2f > d)) {
      loss = fmaxf(0.2f * d * d - 0.7f * d + 0.5f, 0.f) +
             fmaxf(0.9f * m * m - 0.4f * m + 0.03f, 0.f);
    }
    for (int off = 1; off < 64; off <<= 1) loss += __shfl_xor(loss, off, 64);
    if (ln == 0) atomicAdd(out, loss / (float)B);
  }
}

extern "C" void kernel_launch(void* const* d_in, const int* in_sizes, int n_in,
                              void* d_out, int out_size, void* d_ws, size_t ws_size,
                              hipStream_t stream) {
  const float* a      = (const float*)d_in[0];
  const float* b      = (const float*)d_in[1];
  const int*   labels = (const int*)d_in[2];
  const int B = in_sizes[2];
  const int D = in_sizes[0] / B;       // 256
  const int Tr = (B / BN) * 2;         // 256 row partial slots (tj x wn)
  const int Tc = (B / BM) * 2;         // 128 col partial slots (ti x wm)

  char* ws = (char*)d_ws;
  unsigned char* an = (unsigned char*)ws;                    // B*D fp8
  unsigned char* bn = (unsigned char*)(ws + (size_t)B * D);  // B*D fp8
  float* diag     = (float*)(ws + (size_t)2 * B * D);        // B*4
  float* row_part = diag + B;                                // Tr*B*4
  float* col_part = row_part + (size_t)Tr * B;               // Tc*B*4

  norm_kernel<<<B / 4, 256, 0, stream>>>(a, b, (unsigned int*)an,
                                         (unsigned int*)bn, diag,
                                         (float*)d_out, D);

  gemm_max_kernel<<<(B / BM) * (B / BN), 256, 0, stream>>>(
      an, bn, labels, row_part, col_part, B);

  finalize_kernel<<<(2 * B) / 64, 256, 0, stream>>>(
      row_part, col_part, diag, B, Tr, Tc, (float*)d_out);
}